// Round 1
// baseline (442.884 us; speedup 1.0000x reference)
//
#include <hip/hip_runtime.h>
#include <stdint.h>

// Problem constants
#define B_    16
#define N_    256
#define HID_  512
#define H_    8
#define DK_   64
#define FEAT_ 8
#define MLPH_ 64
#define LAM_  0.1f
#define SCALE_ 0.125f   // DK^-0.5

// ---------- helpers ----------
__device__ __forceinline__ uint16_t f32_to_bf16(float x) {
    uint32_t u = __float_as_uint(x);
    u += 0x7fffu + ((u >> 16) & 1u);      // RNE (no NaN/Inf in this data)
    return (uint16_t)(u >> 16);
}
__device__ __forceinline__ float bf16lo(uint32_t pk) { return __uint_as_float(pk << 16); }
__device__ __forceinline__ float bf16hi(uint32_t pk) { return __uint_as_float(pk & 0xffff0000u); }

// ---------- K1: QKV projection, fp32 tiled GEMM ----------
// grid (64, 8, 3), block 256. C = X @ W + b, written in [B,H,N,DK] head layout.
// z: 0=q (scaled by SCALE_), 1=k, 2=v. Tile 64x64, K-step 16, 4x4 per thread.
__global__ __launch_bounds__(256) void proj_kernel(
    const float* __restrict__ q, const float* __restrict__ k, const float* __restrict__ v,
    const float* __restrict__ Wq, const float* __restrict__ bq,
    const float* __restrict__ Wk, const float* __restrict__ bk,
    const float* __restrict__ Wv, const float* __restrict__ bv,
    float* __restrict__ qh, float* __restrict__ kh, float* __restrict__ vh)
{
    int z = blockIdx.z;
    const float* X    = (z == 0) ? q  : (z == 1) ? k  : v;
    const float* W    = (z == 0) ? Wq : (z == 1) ? Wk : Wv;
    const float* bias = (z == 0) ? bq : (z == 1) ? bk : bv;
    float* out        = (z == 0) ? qh : (z == 1) ? kh : vh;
    float scale       = (z == 0) ? SCALE_ : 1.0f;

    int rt0 = blockIdx.x * 64;
    int c0  = blockIdx.y * 64;

    __shared__ __align__(16) float Xs[16][68];  // [k][m], transposed store
    __shared__ __align__(16) float Ws[16][68];  // [k][n]

    int t  = threadIdx.x;
    int tx = t & 15, ty = t >> 4;
    int lr = t >> 2, lk = (t & 3) * 4;  // X load: row 0..63, k-quad
    int wk = t >> 4, wc = (t & 15) * 4; // W load: k-row 0..15, c-quad

    float acc[4][4] = {};

    for (int k0 = 0; k0 < HID_; k0 += 16) {
        float4 xa = *(const float4*)&X[(rt0 + lr) * HID_ + k0 + lk];
        float4 wa = *(const float4*)&W[(k0 + wk) * HID_ + c0 + wc];
        __syncthreads();
        Xs[lk + 0][lr] = xa.x; Xs[lk + 1][lr] = xa.y;
        Xs[lk + 2][lr] = xa.z; Xs[lk + 3][lr] = xa.w;
        *(float4*)&Ws[wk][wc] = wa;
        __syncthreads();
        #pragma unroll
        for (int kk = 0; kk < 16; kk++) {
            float4 a4 = *(const float4*)&Xs[kk][ty * 4];
            float4 b4 = *(const float4*)&Ws[kk][tx * 4];
            float av[4] = {a4.x, a4.y, a4.z, a4.w};
            float bv4[4] = {b4.x, b4.y, b4.z, b4.w};
            #pragma unroll
            for (int i = 0; i < 4; i++)
                #pragma unroll
                for (int j = 0; j < 4; j++)
                    acc[i][j] += av[i] * bv4[j];
        }
    }

    int h = c0 >> 6;  // c-tile == one head
    float4 bsv = *(const float4*)&bias[c0 + tx * 4];
    float bb[4] = {bsv.x, bsv.y, bsv.z, bsv.w};
    #pragma unroll
    for (int i = 0; i < 4; i++) {
        int r = rt0 + ty * 4 + i;
        int b_ = r >> 8, n_ = r & 255;
        float4 o;
        o.x = (acc[i][0] + bb[0]) * scale;
        o.y = (acc[i][1] + bb[1]) * scale;
        o.z = (acc[i][2] + bb[2]) * scale;
        o.w = (acc[i][3] + bb[3]) * scale;
        *(float4*)&out[(((b_ * H_ + h) * N_) + n_) * DK_ + tx * 4] = o;
    }
}

// ---------- K2: per-node MLP halves ----------
// his[b,n,k] = feat@Wa + b1 (b1 folded);  hjsT[b,k,n] = feat@Wb (transposed for
// coalesced per-pair reads). grid (1024, 2), block 256 (4 nodes x 64 k).
__global__ __launch_bounds__(256) void node_mlp_kernel(
    const float* __restrict__ sf, const float* __restrict__ of,
    const float* __restrict__ fsW1, const float* __restrict__ fsb1,
    const float* __restrict__ foW1, const float* __restrict__ fob1,
    float* __restrict__ his_s, float* __restrict__ hjsT_s,
    float* __restrict__ his_o, float* __restrict__ hjsT_o)
{
    int set = blockIdx.y;
    const float* feat = set == 0 ? sf : of;
    const float* W1   = set == 0 ? fsW1 : foW1;
    const float* b1   = set == 0 ? fsb1 : fob1;
    float* his  = set == 0 ? his_s : his_o;
    float* hjsT = set == 0 ? hjsT_s : hjsT_o;

    int t = threadIdx.x;
    int node = blockIdx.x * 4 + (t >> 6);   // wave-uniform -> s_load of feat
    int kk = t & 63;
    int b_ = node >> 8, n_ = node & 255;

    float f[FEAT_];
    #pragma unroll
    for (int i = 0; i < FEAT_; i++) f[i] = feat[node * FEAT_ + i];
    float hi = b1[kk], hj = 0.f;
    #pragma unroll
    for (int i = 0; i < FEAT_; i++) {
        hi += f[i] * W1[i * MLPH_ + kk];
        hj += f[i] * W1[(FEAT_ + i) * MLPH_ + kk];
    }
    his[node * MLPH_ + kk] = hi;
    hjsT[(b_ * MLPH_ + kk) * N_ + n_] = hj;
}

// ---------- K2b: transpose the Wc blocks so the pair kernel can s_load rows ----
__global__ void prep_wct(const float* __restrict__ fsW1, const float* __restrict__ foW1,
                         float* __restrict__ wctS, float* __restrict__ wctO)
{
    int t = threadIdx.x;             // 512 threads: k = t>>3, f = t&7
    int k = t >> 3, f = t & 7;
    wctS[t] = fsW1[(2 * FEAT_ + f) * MLPH_ + k];
    wctO[t] = foW1[(2 * FEAT_ + f) * MLPH_ + k];
}

// ---------- K3: per-pair MLP -> biastot = tree + LAM*(mlp_s + mlp_o) ----------
// grid (N=256 i, B=16), block 256 (thread = j). All weight/his addresses are
// wave-uniform -> scalar loads; inner loop is v_fma(v,s,v). hjsT reads coalesced.
__global__ __launch_bounds__(256) void pair_bias_kernel(
    const float* __restrict__ sf, const float* __restrict__ of,
    const float* __restrict__ wctS, const float* __restrict__ fsW2, const float* __restrict__ fsb2,
    const float* __restrict__ wctO, const float* __restrict__ foW2, const float* __restrict__ fob2,
    const float* __restrict__ his_s, const float* __restrict__ hjsT_s,
    const float* __restrict__ his_o, const float* __restrict__ hjsT_o,
    const float* __restrict__ tree, float* __restrict__ biastot)
{
    int i = blockIdx.x, b = blockIdx.y, j = threadIdx.x;

    float dsv[FEAT_], dov[FEAT_];
    #pragma unroll
    for (int f = 0; f < FEAT_; f++) {
        dsv[f] = fabsf(sf[(b * N_ + i) * FEAT_ + f] - sf[(b * N_ + j) * FEAT_ + f]);
        dov[f] = fabsf(of[(b * N_ + i) * FEAT_ + f] - of[(b * N_ + j) * FEAT_ + f]);
    }
    float acc[H_];
    #pragma unroll
    for (int h = 0; h < H_; h++) acc[h] = fsb2[h] + fob2[h];

    const float* hisS = his_s + (b * N_ + i) * MLPH_;
    const float* hisO = his_o + (b * N_ + i) * MLPH_;
    const float* hjS  = hjsT_s + b * MLPH_ * N_ + j;
    const float* hjO  = hjsT_o + b * MLPH_ * N_ + j;

    #pragma unroll 4
    for (int kk = 0; kk < MLPH_; kk++) {
        float hs = hisS[kk] + hjS[kk * N_];
        float ho = hisO[kk] + hjO[kk * N_];
        #pragma unroll
        for (int f = 0; f < FEAT_; f++) {
            hs += dsv[f] * wctS[kk * 8 + f];
            ho += dov[f] * wctO[kk * 8 + f];
        }
        hs = fmaxf(hs, 0.f);
        ho = fmaxf(ho, 0.f);
        #pragma unroll
        for (int h = 0; h < H_; h++)
            acc[h] += hs * fsW2[kk * H_ + h] + ho * foW2[kk * H_ + h];
    }

    int base = ((b * H_) * N_ + i) * N_ + j;
    #pragma unroll
    for (int h = 0; h < H_; h++) {
        int idx = base + h * N_ * N_;
        biastot[idx] = tree[idx] + LAM_ * acc[h];
    }
}

// ---------- K4: attention (scores + softmax + PV), fused per (b,h,quarter) ----
// grid 512, block 256 (4 waves). K staged in LDS as bf16 (padded rows, conflict-
// free per-lane row reads). Q read via uniform (scalar) loads. V read coalesced
// from global (L1/L2 resident). Block softmax via wave shuffles.
__global__ __launch_bounds__(256) void attn_kernel(
    const float* __restrict__ qh, const float* __restrict__ khg_,
    const float* __restrict__ vhg_, const float* __restrict__ biastot,
    float* __restrict__ ctx)
{
    int blk = blockIdx.x;       // 0..511
    int bh = blk >> 2;          // b*H+h
    int quarter = blk & 3;

    __shared__ __align__(16) uint16_t kh_s[N_ * 66];   // bf16, row stride 66
    __shared__ __align__(16) float s_s[4][N_];
    __shared__ __align__(16) float p_s[N_ * 4];        // [j][i2], float4 rows
    __shared__ __align__(16) float xp[4][4][DK_];      // [g][i2][d]

    int t = threadIdx.x;
    int wave = t >> 6, lane = t & 63;

    const float* khg = khg_ + bh * N_ * DK_;
    const float* vhg = vhg_ + bh * N_ * DK_;

    // stage K as bf16
    for (int s4 = t; s4 < N_ * DK_ / 4; s4 += 256) {
        float4 kv = *(const float4*)(khg + s4 * 4);
        int j = (s4 * 4) >> 6, d = (s4 * 4) & 63;
        uint16_t* dst = &kh_s[j * 66 + d];
        dst[0] = f32_to_bf16(kv.x); dst[1] = f32_to_bf16(kv.y);
        dst[2] = f32_to_bf16(kv.z); dst[3] = f32_to_bf16(kv.w);
    }
    __syncthreads();

    for (int ib = 0; ib < 16; ib++) {
        int i0 = quarter * 64 + ib * 4;
        const float* qrow = qh + (bh * N_ + i0) * DK_;   // uniform -> s_load

        // phase A: thread j computes scores for 4 rows
        {
            int j = t;
            const uint16_t* kr = &kh_s[j * 66];
            float a0 = 0, a1 = 0, a2 = 0, a3 = 0;
            #pragma unroll 4
            for (int d2 = 0; d2 < 32; d2++) {
                uint32_t pk = *(const uint32_t*)&kr[d2 * 2];
                float k0f = bf16lo(pk), k1f = bf16hi(pk);
                int d = d2 * 2;
                a0 += qrow[d] * k0f;           a0 += qrow[d + 1] * k1f;
                a1 += qrow[64 + d] * k0f;      a1 += qrow[64 + d + 1] * k1f;
                a2 += qrow[128 + d] * k0f;     a2 += qrow[128 + d + 1] * k1f;
                a3 += qrow[192 + d] * k0f;     a3 += qrow[192 + d + 1] * k1f;
            }
            const float* br = biastot + (bh * N_ + i0) * N_ + j;
            s_s[0][j] = a0 + br[0];
            s_s[1][j] = a1 + br[N_];
            s_s[2][j] = a2 + br[2 * N_];
            s_s[3][j] = a3 + br[3 * N_];
        }
        __syncthreads();

        // phase B: wave w softmaxes row w (256 elems, 4 per lane)
        {
            float v0 = s_s[wave][lane],       v1 = s_s[wave][lane + 64];
            float v2 = s_s[wave][lane + 128], v3 = s_s[wave][lane + 192];
            float m = fmaxf(fmaxf(v0, v1), fmaxf(v2, v3));
            #pragma unroll
            for (int off = 32; off >= 1; off >>= 1) m = fmaxf(m, __shfl_xor(m, off));
            float e0 = __expf(v0 - m), e1 = __expf(v1 - m);
            float e2 = __expf(v2 - m), e3 = __expf(v3 - m);
            float sum = e0 + e1 + e2 + e3;
            #pragma unroll
            for (int off = 32; off >= 1; off >>= 1) sum += __shfl_xor(sum, off);
            float inv = 1.0f / sum;
            p_s[(lane      ) * 4 + wave] = e0 * inv;
            p_s[(lane +  64) * 4 + wave] = e1 * inv;
            p_s[(lane + 128) * 4 + wave] = e2 * inv;
            p_s[(lane + 192) * 4 + wave] = e3 * inv;
        }
        __syncthreads();

        // phase C: wave g accumulates partial x over its 64 j's; d = lane
        {
            int g = wave, d = lane;
            float a0 = 0, a1 = 0, a2 = 0, a3 = 0;
            const float* vcol = vhg + (g * 64) * DK_ + d;
            const float4* p4 = (const float4*)p_s;
            #pragma unroll 8
            for (int jj = 0; jj < 64; jj++) {
                int j = g * 64 + jj;
                float vv = vcol[jj * DK_];       // coalesced across lanes
                float4 pv = p4[j];               // uniform -> LDS broadcast b128
                a0 += pv.x * vv; a1 += pv.y * vv;
                a2 += pv.z * vv; a3 += pv.w * vv;
            }
            xp[g][0][d] = a0; xp[g][1][d] = a1; xp[g][2][d] = a2; xp[g][3][d] = a3;
        }
        __syncthreads();

        // reduce across the 4 groups, write ctx (coalesced)
        {
            int i2 = wave, d = lane;
            float x = xp[0][i2][d] + xp[1][i2][d] + xp[2][i2][d] + xp[3][i2][d];
            ctx[(bh * N_ + i0 + i2) * DK_ + d] = x;
        }
        __syncthreads();
    }
}

// ---------- K5: output projection ----------
// grid (64, 8), block 256. X gathered from head-layout ctx; out = X@Wo + bo.
__global__ __launch_bounds__(256) void outproj_kernel(
    const float* __restrict__ ctx, const float* __restrict__ Wo,
    const float* __restrict__ bo, float* __restrict__ out)
{
    int rt0 = blockIdx.x * 64;
    int c0  = blockIdx.y * 64;
    __shared__ __align__(16) float Xs[16][68];
    __shared__ __align__(16) float Ws[16][68];
    int t = threadIdx.x;
    int tx = t & 15, ty = t >> 4;
    int lr = t >> 2, lk = (t & 3) * 4;
    int wk = t >> 4, wc = (t & 15) * 4;
    int r = rt0 + lr;
    int b_ = r >> 8, n_ = r & 255;
    float acc[4][4] = {};

    for (int k0 = 0; k0 < HID_; k0 += 16) {
        int kidx = k0 + lk;       // quad stays within one head block
        float4 xa = *(const float4*)&ctx[((b_ * H_ + (kidx >> 6)) * N_ + n_) * DK_ + (kidx & 63)];
        float4 wa = *(const float4*)&Wo[(k0 + wk) * HID_ + c0 + wc];
        __syncthreads();
        Xs[lk + 0][lr] = xa.x; Xs[lk + 1][lr] = xa.y;
        Xs[lk + 2][lr] = xa.z; Xs[lk + 3][lr] = xa.w;
        *(float4*)&Ws[wk][wc] = wa;
        __syncthreads();
        #pragma unroll
        for (int kk = 0; kk < 16; kk++) {
            float4 a4 = *(const float4*)&Xs[kk][ty * 4];
            float4 b4 = *(const float4*)&Ws[kk][tx * 4];
            float av[4] = {a4.x, a4.y, a4.z, a4.w};
            float bv4[4] = {b4.x, b4.y, b4.z, b4.w};
            #pragma unroll
            for (int i = 0; i < 4; i++)
                #pragma unroll
                for (int j = 0; j < 4; j++)
                    acc[i][j] += av[i] * bv4[j];
        }
    }

    float4 bv4 = *(const float4*)&bo[c0 + tx * 4];
    float bb[4] = {bv4.x, bv4.y, bv4.z, bv4.w};
    #pragma unroll
    for (int i = 0; i < 4; i++) {
        int rr = rt0 + ty * 4 + i;
        float4 o;
        o.x = acc[i][0] + bb[0]; o.y = acc[i][1] + bb[1];
        o.z = acc[i][2] + bb[2]; o.w = acc[i][3] + bb[3];
        *(float4*)&out[rr * HID_ + c0 + tx * 4] = o;
    }
}

// ---------- launch ----------
extern "C" void kernel_launch(void* const* d_in, const int* in_sizes, int n_in,
                              void* d_out, int out_size, void* d_ws, size_t ws_size,
                              hipStream_t stream)
{
    const float* q    = (const float*)d_in[0];
    const float* k    = (const float*)d_in[1];
    const float* v    = (const float*)d_in[2];
    const float* tree = (const float*)d_in[3];
    const float* sf   = (const float*)d_in[4];
    const float* of   = (const float*)d_in[5];
    const float* Wq   = (const float*)d_in[6];
    const float* bq   = (const float*)d_in[7];
    const float* Wk   = (const float*)d_in[8];
    const float* bk   = (const float*)d_in[9];
    const float* Wv   = (const float*)d_in[10];
    const float* bv   = (const float*)d_in[11];
    const float* Wo   = (const float*)d_in[12];
    const float* bo   = (const float*)d_in[13];
    const float* fsW1 = (const float*)d_in[14];
    const float* fsb1 = (const float*)d_in[15];
    const float* fsW2 = (const float*)d_in[16];
    const float* fsb2 = (const float*)d_in[17];
    const float* foW1 = (const float*)d_in[18];
    const float* fob1 = (const float*)d_in[19];
    const float* foW2 = (const float*)d_in[20];
    const float* fob2 = (const float*)d_in[21];

    // workspace layout (floats); total 17,826,816 floats = 71.3 MB
    float* ws      = (float*)d_ws;
    float* qh      = ws;                    // 2,097,152
    float* kh      = ws + 2097152;          // 2,097,152
    float* vh      = ws + 4194304;          // 2,097,152
    float* ctx     = ws + 6291456;          // 2,097,152
    float* his_s   = ws + 8388608;          //   262,144
    float* hjsT_s  = his_s + 262144;        //   262,144
    float* his_o   = hjsT_s + 262144;       //   262,144
    float* hjsT_o  = his_o + 262144;        //   262,144
    float* wctS    = hjsT_o + 262144;       //       512
    float* wctO    = wctS + 512;            //       512
    float* biastot = wctO + 512;            // 8,388,608

    proj_kernel<<<dim3(64, 8, 3), 256, 0, stream>>>(q, k, v, Wq, bq, Wk, bk, Wv, bv, qh, kh, vh);
    node_mlp_kernel<<<dim3(1024, 2), 256, 0, stream>>>(sf, of, fsW1, fsb1, foW1, fob1,
                                                       his_s, hjsT_s, his_o, hjsT_o);
    prep_wct<<<1, 512, 0, stream>>>(fsW1, foW1, wctS, wctO);
    pair_bias_kernel<<<dim3(256, 16), 256, 0, stream>>>(sf, of, wctS, fsW2, fsb2, wctO, foW2, fob2,
                                                        his_s, hjsT_s, his_o, hjsT_o, tree, biastot);
    attn_kernel<<<512, 256, 0, stream>>>(qh, kh, vh, biastot, ctx);
    outproj_kernel<<<dim3(64, 8), 256, 0, stream>>>(ctx, Wo, bo, (float*)d_out);
}

// Round 3
// 307.845 us; speedup vs baseline: 1.4387x; 1.4387x over previous
//
#include <hip/hip_runtime.h>
#include <stdint.h>

// Problem constants
#define B_    16
#define N_    256
#define HID_  512
#define H_    8
#define DK_   64
#define FEAT_ 8
#define MLPH_ 64
#define LAM_  0.1f
#define SCALE_ 0.125f   // DK^-0.5

typedef short bf16x8 __attribute__((ext_vector_type(8)));
typedef float f32x4  __attribute__((ext_vector_type(4)));

union U8 { uint4 u; bf16x8 h; ushort s[8]; };

__device__ __forceinline__ uint16_t f32_to_bf16(float x) {
    uint32_t u = __float_as_uint(x);
    u += 0x7fffu + ((u >> 16) & 1u);      // RNE (no NaN/Inf in this data)
    return (uint16_t)(u >> 16);
}

// ---------- K1: QKV projection, bf16 MFMA GEMM ----------
// grid (64, 8, 3), block 256 (4 waves). Tile M=64 (wave=16 rows), N=64 (=1 head),
// K-chunk 32. Writes qh/kh/vh in bf16 [B,H,N,DK] head layout (q pre-scaled).
// NOTE: grid.x MUST be 64 (=4096 rows / 64-row tile) — 32 was the R2 bug.
__global__ __launch_bounds__(256, 4) void proj_kernel(
    const float* __restrict__ q, const float* __restrict__ k, const float* __restrict__ v,
    const float* __restrict__ Wq, const float* __restrict__ bq,
    const float* __restrict__ Wk, const float* __restrict__ bk,
    const float* __restrict__ Wv, const float* __restrict__ bv,
    ushort* __restrict__ qh, ushort* __restrict__ kh, ushort* __restrict__ vh)
{
    int z = blockIdx.z;
    const float* X    = (z == 0) ? q  : (z == 1) ? k  : v;
    const float* W    = (z == 0) ? Wq : (z == 1) ? Wk : Wv;
    const float* bias = (z == 0) ? bq : (z == 1) ? bk : bv;
    ushort* out       = (z == 0) ? qh : (z == 1) ? kh : vh;
    float scale       = (z == 0) ? SCALE_ : 1.0f;

    int m0 = blockIdx.x * 64;
    int h  = blockIdx.y;
    int c0 = h * 64;

    __shared__ __align__(16) ushort Xs[64 * 40];
    __shared__ __align__(16) ushort Ws[64 * 40];

    int t = threadIdx.x;
    int wave = t >> 6, lane = t & 63;
    int l15 = lane & 15, qd = lane >> 4;

    f32x4 acc[4] = {};   // 4 N-tiles of 16, rows = wave*16 + qd*4 + r

    for (int k0 = 0; k0 < HID_; k0 += 32) {
        __syncthreads();
        // stage X tile 64x32 -> bf16
        #pragma unroll
        for (int u = t; u < 512; u += 256) {
            int r = u >> 3, c4 = (u & 7) * 4;
            float4 xv = *(const float4*)&X[(m0 + r) * HID_ + k0 + c4];
            ushort4 o;
            o.x = f32_to_bf16(xv.x); o.y = f32_to_bf16(xv.y);
            o.z = f32_to_bf16(xv.z); o.w = f32_to_bf16(xv.w);
            *(ushort4*)&Xs[r * 40 + c4] = o;
        }
        // stage W tile 32x64 transposed (Ws[n][kk]), packed k-pairs
        {
            int kr = t & 15, nq = t >> 4;          // k-pair 0..15, n-quad 0..15
            float4 w0 = *(const float4*)&W[(k0 + 2 * kr) * HID_ + c0 + nq * 4];
            float4 w1 = *(const float4*)&W[(k0 + 2 * kr + 1) * HID_ + c0 + nq * 4];
            const float* a0 = &w0.x; const float* a1 = &w1.x;
            #pragma unroll
            for (int i = 0; i < 4; i++) {
                uint32_t pk = (uint32_t)f32_to_bf16(a0[i]) | ((uint32_t)f32_to_bf16(a1[i]) << 16);
                *(uint32_t*)&Ws[(nq * 4 + i) * 40 + 2 * kr] = pk;
            }
        }
        __syncthreads();
        bf16x8 af = *(const bf16x8*)&Xs[(wave * 16 + l15) * 40 + qd * 8];
        #pragma unroll
        for (int nt = 0; nt < 4; nt++) {
            bf16x8 bf = *(const bf16x8*)&Ws[(nt * 16 + l15) * 40 + qd * 8];
            acc[nt] = __builtin_amdgcn_mfma_f32_16x16x32_bf16(af, bf, acc[nt], 0, 0, 0);
        }
    }

    // epilogue: bias + scale, bf16 store in head layout
    #pragma unroll
    for (int nt = 0; nt < 4; nt++) {
        float bb = bias[c0 + nt * 16 + l15];
        #pragma unroll
        for (int r = 0; r < 4; r++) {
            int m = m0 + wave * 16 + qd * 4 + r;
            int b_ = m >> 8, n_ = m & 255;
            float val = (acc[nt][r] + bb) * scale;
            out[(((b_ * H_ + h) * N_) + n_) * DK_ + nt * 16 + l15] = f32_to_bf16(val);
        }
    }
}

// ---------- K2: per-node MLP halves (fp32, tiny) ----------
__global__ __launch_bounds__(256) void node_mlp_kernel(
    const float* __restrict__ sf, const float* __restrict__ of,
    const float* __restrict__ fsW1, const float* __restrict__ fsb1,
    const float* __restrict__ foW1, const float* __restrict__ fob1,
    float* __restrict__ his_s, float* __restrict__ hjsT_s,
    float* __restrict__ his_o, float* __restrict__ hjsT_o)
{
    int set = blockIdx.y;
    const float* feat = set == 0 ? sf : of;
    const float* W1   = set == 0 ? fsW1 : foW1;
    const float* b1   = set == 0 ? fsb1 : fob1;
    float* his  = set == 0 ? his_s : his_o;
    float* hjsT = set == 0 ? hjsT_s : hjsT_o;

    int t = threadIdx.x;
    int node = blockIdx.x * 4 + (t >> 6);
    int kk = t & 63;
    int b_ = node >> 8, n_ = node & 255;

    float f[FEAT_];
    #pragma unroll
    for (int i = 0; i < FEAT_; i++) f[i] = feat[node * FEAT_ + i];
    float hi = b1[kk], hj = 0.f;
    #pragma unroll
    for (int i = 0; i < FEAT_; i++) {
        hi += f[i] * W1[i * MLPH_ + kk];
        hj += f[i] * W1[(FEAT_ + i) * MLPH_ + kk];
    }
    his[node * MLPH_ + kk] = hi;
    hjsT[(b_ * MLPH_ + kk) * N_ + n_] = hj;
}

// ---------- K2b: transpose Wc blocks ----------
__global__ void prep_wct(const float* __restrict__ fsW1, const float* __restrict__ foW1,
                         float* __restrict__ wctS, float* __restrict__ wctO)
{
    int t = threadIdx.x;
    int k = t >> 3, f = t & 7;
    wctS[t] = fsW1[(2 * FEAT_ + f) * MLPH_ + k];
    wctO[t] = foW1[(2 * FEAT_ + f) * MLPH_ + k];
}

// ---------- K3: per-pair MLP -> biastot = tree + LAM*(mlp_s + mlp_o) ----------
__global__ __launch_bounds__(256) void pair_bias_kernel(
    const float* __restrict__ sf, const float* __restrict__ of,
    const float* __restrict__ wctS, const float* __restrict__ fsW2, const float* __restrict__ fsb2,
    const float* __restrict__ wctO, const float* __restrict__ foW2, const float* __restrict__ fob2,
    const float* __restrict__ his_s, const float* __restrict__ hjsT_s,
    const float* __restrict__ his_o, const float* __restrict__ hjsT_o,
    const float* __restrict__ tree, float* __restrict__ biastot)
{
    int i = blockIdx.x, b = blockIdx.y, j = threadIdx.x;

    float dsv[FEAT_], dov[FEAT_];
    #pragma unroll
    for (int f = 0; f < FEAT_; f++) {
        dsv[f] = fabsf(sf[(b * N_ + i) * FEAT_ + f] - sf[(b * N_ + j) * FEAT_ + f]);
        dov[f] = fabsf(of[(b * N_ + i) * FEAT_ + f] - of[(b * N_ + j) * FEAT_ + f]);
    }
    float acc[H_];
    #pragma unroll
    for (int h = 0; h < H_; h++) acc[h] = fsb2[h] + fob2[h];

    const float* hisS = his_s + (b * N_ + i) * MLPH_;
    const float* hisO = his_o + (b * N_ + i) * MLPH_;
    const float* hjS  = hjsT_s + b * MLPH_ * N_ + j;
    const float* hjO  = hjsT_o + b * MLPH_ * N_ + j;

    #pragma unroll 4
    for (int kk = 0; kk < MLPH_; kk++) {
        float hs = hisS[kk] + hjS[kk * N_];
        float ho = hisO[kk] + hjO[kk * N_];
        #pragma unroll
        for (int f = 0; f < FEAT_; f++) {
            hs += dsv[f] * wctS[kk * 8 + f];
            ho += dov[f] * wctO[kk * 8 + f];
        }
        hs = fmaxf(hs, 0.f);
        ho = fmaxf(ho, 0.f);
        #pragma unroll
        for (int h = 0; h < H_; h++)
            acc[h] += hs * fsW2[kk * H_ + h] + ho * foW2[kk * H_ + h];
    }

    int base = ((b * H_) * N_ + i) * N_ + j;
    #pragma unroll
    for (int h = 0; h < H_; h++) {
        int idx = base + h * N_ * N_;
        biastot[idx] = tree[idx] + LAM_ * acc[h];
    }
}

// ---------- K4: MFMA attention ----------
// grid 512 = (b*H, quarter). block 256 = 4 waves; wave owns 16 Q-rows.
// LDS: K [256][72] bf16 (later overlaid by P [4 waves][16][264]), Vt [64][264] bf16.
// QK^T and PV both via mfma_f32_16x16x32_bf16; softmax in registers.
__global__ __launch_bounds__(256, 2) void attn_kernel(
    const ushort* __restrict__ qh, const ushort* __restrict__ kh,
    const ushort* __restrict__ vh, const float* __restrict__ biastot,
    float* __restrict__ ctx)
{
    __shared__ __align__(16) ushort bufKP[256 * 72];     // 36,864 B; K then P overlay
    __shared__ __align__(16) ushort bufV[64 * 264];      // 33,792 B; Vt[d][j]

    int blk = blockIdx.x;
    int bh = blk >> 2;
    int quarter = blk & 3;

    int t = threadIdx.x;
    int wave = t >> 6, lane = t & 63;
    int l15 = lane & 15, qd = lane >> 4;
    int i0w = quarter * 64 + wave * 16;

    const ushort* khb = kh + (size_t)bh * N_ * DK_;
    const ushort* vhb = vh + (size_t)bh * N_ * DK_;

    // ---- stage K (row-major, stride 72) ----
    #pragma unroll
    for (int u = t; u < 2048; u += 256) {
        int j = u >> 3, seg = (u & 7) * 8;
        uint4 kv = *(const uint4*)&khb[j * DK_ + seg];
        *(uint4*)&bufKP[j * 72 + seg] = kv;
    }
    // ---- stage V transposed: Vt[d][j], stride 264, packed j-pairs ----
    #pragma unroll
    for (int u = t; u < 1024; u += 256) {
        int rp = u & 127, d0 = (u >> 7) * 8;
        U8 v0, v1;
        v0.u = *(const uint4*)&vhb[(2 * rp) * DK_ + d0];
        v1.u = *(const uint4*)&vhb[(2 * rp + 1) * DK_ + d0];
        #pragma unroll
        for (int jj = 0; jj < 8; jj++) {
            uint32_t pk = (uint32_t)v0.s[jj] | ((uint32_t)v1.s[jj] << 16);
            *(uint32_t*)&bufV[(d0 + jj) * 264 + 2 * rp] = pk;
        }
    }
    __syncthreads();

    // ---- QK^T: S[16 nt] tiles, rows i0w + qd*4 + r, cols nt*16 + l15 ----
    bf16x8 a0, a1;
    {
        size_t qb = ((size_t)bh * N_ + i0w + l15) * DK_;
        U8 t0, t1;
        t0.u = *(const uint4*)&qh[qb + qd * 8];
        t1.u = *(const uint4*)&qh[qb + 32 + qd * 8];
        a0 = t0.h; a1 = t1.h;
    }
    f32x4 S[16];
    #pragma unroll
    for (int nt = 0; nt < 16; nt++) {
        f32x4 acc = {};
        bf16x8 b0 = *(const bf16x8*)&bufKP[(nt * 16 + l15) * 72 + qd * 8];
        bf16x8 b1 = *(const bf16x8*)&bufKP[(nt * 16 + l15) * 72 + 32 + qd * 8];
        acc = __builtin_amdgcn_mfma_f32_16x16x32_bf16(a0, b0, acc, 0, 0, 0);
        acc = __builtin_amdgcn_mfma_f32_16x16x32_bf16(a1, b1, acc, 0, 0, 0);
        S[nt] = acc;
    }

    // ---- bias add ----
    {
        const float* bb = biastot + ((size_t)bh * N_ + i0w + qd * 4) * N_ + l15;
        #pragma unroll
        for (int nt = 0; nt < 16; nt++)
            #pragma unroll
            for (int r = 0; r < 4; r++)
                S[nt][r] += bb[(size_t)r * N_ + nt * 16];
    }

    // ---- softmax (rows live in regs across 16 lanes of same qd) ----
    float mx[4], sm[4];
    #pragma unroll
    for (int r = 0; r < 4; r++) mx[r] = -1e30f;
    #pragma unroll
    for (int nt = 0; nt < 16; nt++)
        #pragma unroll
        for (int r = 0; r < 4; r++) mx[r] = fmaxf(mx[r], S[nt][r]);
    #pragma unroll
    for (int r = 0; r < 4; r++) {
        #pragma unroll
        for (int m = 1; m <= 8; m <<= 1) mx[r] = fmaxf(mx[r], __shfl_xor(mx[r], m));
    }
    #pragma unroll
    for (int r = 0; r < 4; r++) sm[r] = 0.f;
    #pragma unroll
    for (int nt = 0; nt < 16; nt++)
        #pragma unroll
        for (int r = 0; r < 4; r++) {
            float e = __expf(S[nt][r] - mx[r]);
            S[nt][r] = e;
            sm[r] += e;
        }
    #pragma unroll
    for (int r = 0; r < 4; r++) {
        #pragma unroll
        for (int m = 1; m <= 8; m <<= 1) sm[r] += __shfl_xor(sm[r], m);
        sm[r] = 1.0f / sm[r];
    }

    __syncthreads();   // all waves done reading K -> safe to overlay P

    // ---- write P (bf16) into K buffer region; per-wave [16][264] ----
    {
        uint32_t* Pw = (uint32_t*)&bufKP[wave * 16 * 264];
        #pragma unroll
        for (int nt = 0; nt < 16; nt++)
            #pragma unroll
            for (int r = 0; r < 4; r++) {
                float p = S[nt][r] * sm[r];
                float po = __shfl_xor(p, 1);
                uint32_t pk = (uint32_t)f32_to_bf16(p) | ((uint32_t)f32_to_bf16(po) << 16);
                if ((lane & 1) == 0)
                    Pw[(qd * 4 + r) * 132 + nt * 8 + (l15 >> 1)] = pk;
            }
    }

    // ---- PV: O[4 d-tiles], contraction over 256 j in 8 chunks ----
    const ushort* Pw = &bufKP[wave * 16 * 264];
    f32x4 O[4] = {};
    #pragma unroll
    for (int ks = 0; ks < 8; ks++) {
        int j0 = ks * 32;
        bf16x8 pa = *(const bf16x8*)&Pw[l15 * 264 + j0 + qd * 8];
        #pragma unroll
        for (int ntd = 0; ntd < 4; ntd++) {
            bf16x8 vb = *(const bf16x8*)&bufV[(ntd * 16 + l15) * 264 + j0 + qd * 8];
            O[ntd] = __builtin_amdgcn_mfma_f32_16x16x32_bf16(pa, vb, O[ntd], 0, 0, 0);
        }
    }

    // ---- write ctx fp32 [bh][i][d] ----
    #pragma unroll
    for (int ntd = 0; ntd < 4; ntd++)
        #pragma unroll
        for (int r = 0; r < 4; r++)
            ctx[((size_t)bh * N_ + i0w + qd * 4 + r) * DK_ + ntd * 16 + l15] = O[ntd][r];
}

// ---------- K5: output projection (fp32 tiled GEMM) ----------
__global__ __launch_bounds__(256) void outproj_kernel(
    const float* __restrict__ ctx, const float* __restrict__ Wo,
    const float* __restrict__ bo, float* __restrict__ out)
{
    int rt0 = blockIdx.x * 64;
    int c0  = blockIdx.y * 64;
    __shared__ __align__(16) float Xs[16][68];
    __shared__ __align__(16) float Ws[16][68];
    int t = threadIdx.x;
    int tx = t & 15, ty = t >> 4;
    int lr = t >> 2, lk = (t & 3) * 4;
    int wk = t >> 4, wc = (t & 15) * 4;
    int r = rt0 + lr;
    int b_ = r >> 8, n_ = r & 255;
    float acc[4][4] = {};

    for (int k0 = 0; k0 < HID_; k0 += 16) {
        int kidx = k0 + lk;
        float4 xa = *(const float4*)&ctx[((b_ * H_ + (kidx >> 6)) * N_ + n_) * DK_ + (kidx & 63)];
        float4 wa = *(const float4*)&Wo[(k0 + wk) * HID_ + c0 + wc];
        __syncthreads();
        Xs[lk + 0][lr] = xa.x; Xs[lk + 1][lr] = xa.y;
        Xs[lk + 2][lr] = xa.z; Xs[lk + 3][lr] = xa.w;
        *(float4*)&Ws[wk][wc] = wa;
        __syncthreads();
        #pragma unroll
        for (int kk = 0; kk < 16; kk++) {
            float4 a4 = *(const float4*)&Xs[kk][ty * 4];
            float4 b4 = *(const float4*)&Ws[kk][tx * 4];
            float av[4] = {a4.x, a4.y, a4.z, a4.w};
            float bv4[4] = {b4.x, b4.y, b4.z, b4.w};
            #pragma unroll
            for (int i = 0; i < 4; i++)
                #pragma unroll
                for (int j = 0; j < 4; j++)
                    acc[i][j] += av[i] * bv4[j];
        }
    }

    float4 bv4 = *(const float4*)&bo[c0 + tx * 4];
    float bb[4] = {bv4.x, bv4.y, bv4.z, bv4.w};
    #pragma unroll
    for (int i = 0; i < 4; i++) {
        int rr = rt0 + ty * 4 + i;
        float4 o;
        o.x = acc[i][0] + bb[0]; o.y = acc[i][1] + bb[1];
        o.z = acc[i][2] + bb[2]; o.w = acc[i][3] + bb[3];
        *(float4*)&out[rr * HID_ + c0 + tx * 4] = o;
    }
}

// ---------- launch ----------
extern "C" void kernel_launch(void* const* d_in, const int* in_sizes, int n_in,
                              void* d_out, int out_size, void* d_ws, size_t ws_size,
                              hipStream_t stream)
{
    const float* q    = (const float*)d_in[0];
    const float* k    = (const float*)d_in[1];
    const float* v    = (const float*)d_in[2];
    const float* tree = (const float*)d_in[3];
    const float* sf   = (const float*)d_in[4];
    const float* of   = (const float*)d_in[5];
    const float* Wq   = (const float*)d_in[6];
    const float* bq   = (const float*)d_in[7];
    const float* Wk   = (const float*)d_in[8];
    const float* bk   = (const float*)d_in[9];
    const float* Wv   = (const float*)d_in[10];
    const float* bv   = (const float*)d_in[11];
    const float* Wo   = (const float*)d_in[12];
    const float* bo   = (const float*)d_in[13];
    const float* fsW1 = (const float*)d_in[14];
    const float* fsb1 = (const float*)d_in[15];
    const float* fsW2 = (const float*)d_in[16];
    const float* fsb2 = (const float*)d_in[17];
    const float* foW1 = (const float*)d_in[18];
    const float* fob1 = (const float*)d_in[19];
    const float* foW2 = (const float*)d_in[20];
    const float* fob2 = (const float*)d_in[21];

    // workspace layout (bytes)
    char* ws = (char*)d_ws;
    ushort* qh     = (ushort*)(ws + 0);           // 4,194,304 B (bf16)
    ushort* kh     = (ushort*)(ws + 4194304);     // 4,194,304 B
    ushort* vh     = (ushort*)(ws + 8388608);     // 4,194,304 B
    float*  ctx    = (float*)(ws + 12582912);     // 8,388,608 B
    float*  his_s  = (float*)(ws + 20971520);     // 1,048,576 B
    float*  hjsT_s = (float*)(ws + 22020096);     // 1,048,576 B
    float*  his_o  = (float*)(ws + 23068672);     // 1,048,576 B
    float*  hjsT_o = (float*)(ws + 24117248);     // 1,048,576 B
    float*  wctS   = (float*)(ws + 25165824);     //     2,048 B
    float*  wctO   = (float*)(ws + 25167872);     //     2,048 B
    float*  biastot= (float*)(ws + 25169920);     // 33,554,432 B  (total ~58.7 MB)

    proj_kernel<<<dim3(64, 8, 3), 256, 0, stream>>>(q, k, v, Wq, bq, Wk, bk, Wv, bv, qh, kh, vh);
    node_mlp_kernel<<<dim3(1024, 2), 256, 0, stream>>>(sf, of, fsW1, fsb1, foW1, fob1,
                                                       his_s, hjsT_s, his_o, hjsT_o);
    prep_wct<<<1, 512, 0, stream>>>(fsW1, foW1, wctS, wctO);
    pair_bias_kernel<<<dim3(256, 16), 256, 0, stream>>>(sf, of, wctS, fsW2, fsb2, wctO, foW2, fob2,
                                                        his_s, hjsT_s, his_o, hjsT_o, tree, biastot);
    attn_kernel<<<512, 256, 0, stream>>>(qh, kh, vh, biastot, ctx);
    outproj_kernel<<<dim3(64, 8), 256, 0, stream>>>(ctx, Wo, bo, (float*)d_out);
}

// Round 7
// 276.650 us; speedup vs baseline: 1.6009x; 1.1128x over previous
//
#include <hip/hip_runtime.h>
#include <stdint.h>

// Problem constants
#define B_    16
#define N_    256
#define HID_  512
#define H_    8
#define DK_   64
#define FEAT_ 8
#define MLPH_ 64
#define LAM_  0.1f
#define SCALE_ 0.125f   // DK^-0.5

typedef short bf16x8 __attribute__((ext_vector_type(8)));
typedef float f32x4  __attribute__((ext_vector_type(4)));

union U8 { uint4 u; bf16x8 h; ushort s[8]; };

__device__ __forceinline__ uint16_t f32_to_bf16(float x) {
    uint32_t u = __float_as_uint(x);
    u += 0x7fffu + ((u >> 16) & 1u);      // RNE (no NaN/Inf in this data)
    return (uint16_t)(u >> 16);
}
__device__ __forceinline__ float bf16_to_f32(uint16_t v) {
    return __uint_as_float(((uint32_t)v) << 16);
}

// ---------- K1: QKV projection, bf16 MFMA GEMM (unchanged) ----------
__global__ __launch_bounds__(256, 4) void proj_kernel(
    const float* __restrict__ q, const float* __restrict__ k, const float* __restrict__ v,
    const float* __restrict__ Wq, const float* __restrict__ bq,
    const float* __restrict__ Wk, const float* __restrict__ bk,
    const float* __restrict__ Wv, const float* __restrict__ bv,
    ushort* __restrict__ qh, ushort* __restrict__ kh, ushort* __restrict__ vh)
{
    int z = blockIdx.z;
    const float* X    = (z == 0) ? q  : (z == 1) ? k  : v;
    const float* W    = (z == 0) ? Wq : (z == 1) ? Wk : Wv;
    const float* bias = (z == 0) ? bq : (z == 1) ? bk : bv;
    ushort* out       = (z == 0) ? qh : (z == 1) ? kh : vh;
    float scale       = (z == 0) ? SCALE_ : 1.0f;

    int m0 = blockIdx.x * 64;
    int h  = blockIdx.y;
    int c0 = h * 64;

    __shared__ __align__(16) ushort Xs[64 * 40];
    __shared__ __align__(16) ushort Ws[64 * 40];

    int t = threadIdx.x;
    int wave = t >> 6, lane = t & 63;
    int l15 = lane & 15, qd = lane >> 4;

    f32x4 acc[4] = {};

    for (int k0 = 0; k0 < HID_; k0 += 32) {
        __syncthreads();
        #pragma unroll
        for (int u = t; u < 512; u += 256) {
            int r = u >> 3, c4 = (u & 7) * 4;
            float4 xv = *(const float4*)&X[(m0 + r) * HID_ + k0 + c4];
            ushort4 o;
            o.x = f32_to_bf16(xv.x); o.y = f32_to_bf16(xv.y);
            o.z = f32_to_bf16(xv.z); o.w = f32_to_bf16(xv.w);
            *(ushort4*)&Xs[r * 40 + c4] = o;
        }
        {
            int kr = t & 15, nq = t >> 4;
            float4 w0 = *(const float4*)&W[(k0 + 2 * kr) * HID_ + c0 + nq * 4];
            float4 w1 = *(const float4*)&W[(k0 + 2 * kr + 1) * HID_ + c0 + nq * 4];
            const float* a0 = &w0.x; const float* a1 = &w1.x;
            #pragma unroll
            for (int i = 0; i < 4; i++) {
                uint32_t pk = (uint32_t)f32_to_bf16(a0[i]) | ((uint32_t)f32_to_bf16(a1[i]) << 16);
                *(uint32_t*)&Ws[(nq * 4 + i) * 40 + 2 * kr] = pk;
            }
        }
        __syncthreads();
        bf16x8 af = *(const bf16x8*)&Xs[(wave * 16 + l15) * 40 + qd * 8];
        #pragma unroll
        for (int nt = 0; nt < 4; nt++) {
            bf16x8 bf = *(const bf16x8*)&Ws[(nt * 16 + l15) * 40 + qd * 8];
            acc[nt] = __builtin_amdgcn_mfma_f32_16x16x32_bf16(af, bf, acc[nt], 0, 0, 0);
        }
    }

    #pragma unroll
    for (int nt = 0; nt < 4; nt++) {
        float bb = bias[c0 + nt * 16 + l15];
        #pragma unroll
        for (int r = 0; r < 4; r++) {
            int m = m0 + wave * 16 + qd * 4 + r;
            int b_ = m >> 8, n_ = m & 255;
            float val = (acc[nt][r] + bb) * scale;
            out[(((b_ * H_ + h) * N_) + n_) * DK_ + nt * 16 + l15] = f32_to_bf16(val);
        }
    }
}

// ---------- K2: per-node i-side MLP table (hisC only) ----------
__global__ __launch_bounds__(256) void node_prep_kernel(
    const float* __restrict__ sf, const float* __restrict__ of,
    const float* __restrict__ fsW1, const float* __restrict__ fsb1,
    const float* __restrict__ foW1, const float* __restrict__ fob1,
    float* __restrict__ hisC)
{
    int t = threadIdx.x;
    int node = blockIdx.x * 2 + (t >> 7);
    int c = t & 127;
    int set = c >> 6, kk = c & 63;
    const float* W1 = set ? foW1 : fsW1;
    const float* fr = (set ? of : sf) + node * FEAT_;
    float a = (set ? fob1 : fsb1)[kk];
    #pragma unroll
    for (int f = 0; f < FEAT_; f++) a += fr[f] * W1[f * 64 + kk];
    hisC[node * 128 + c] = a;
}

// ---------- K3: pair-MLP via MFMA -> mlpb = bf16(LAM*(mlp_s+mlp_o+b2)) ----------
// R7: explicit __syncthreads() fences around both LDS round trips (h and tbuf).
// Root-cause theory: strict-aliasing let the compiler hoist ds_reads above the
// same-wave ds_writes (write ushort/uint32, read short8) -> stale-LDS reads.
// s_barrier is a type-agnostic LDS fence the compiler cannot cross.
#define HSTRIDE 136
__global__ __launch_bounds__(256) void pair_bias_mfma(
    const float* __restrict__ sf, const float* __restrict__ of,
    const float* __restrict__ hisC,
    const float* __restrict__ fsW1, const float* __restrict__ foW1,
    const float* __restrict__ fsW2, const float* __restrict__ foW2,
    const float* __restrict__ fsb2, const float* __restrict__ fob2,
    ushort* __restrict__ mlpb)
{
    __shared__ __align__(16) ushort hbuf[4][16 * HSTRIDE];  // per-wave h
    __shared__ __align__(16) ushort Wst1[128 * 40];         // GEMM1 B: [n=128][k=32]
    __shared__ __align__(16) ushort Wst2[16 * HSTRIDE];     // GEMM2 B: [n=16][k2=128]
    __shared__ float hisbuf[128];
    __shared__ __align__(4) ushort tbuf[4][8 * 16];

    int i = blockIdx.x, b = blockIdx.y;
    int t = threadIdx.x;
    int wave = t >> 6, lane = t & 63;
    int l15 = lane & 15, qd = lane >> 4;

    if (t < 128) hisbuf[t] = hisC[(b * N_ + i) * 128 + t];

    // stage Wstack1 transposed [n][k]: k 0..7 = Wc_s, 8..15 = Wb_s (n<64);
    // 16..23 = Wc_o, 24..31 = Wb_o (n>=64); zero elsewhere.
    for (int e = t; e < 4096; e += 256) {
        int n = e >> 5, kk = e & 31, q = kk >> 3, u = kk & 7;
        float x = 0.f;
        if (n < 64) {
            if (q == 0) x = fsW1[(16 + u) * 64 + n];
            else if (q == 1) x = fsW1[(8 + u) * 64 + n];
        } else {
            int n2 = n - 64;
            if (q == 2) x = foW1[(16 + u) * 64 + n2];
            else if (q == 3) x = foW1[(8 + u) * 64 + n2];
        }
        Wst1[n * 40 + kk] = f32_to_bf16(x);
    }
    // stage Wstack2 [n][k2]: n<8 -> W2stack[k2][n]; n>=8 -> 0
    for (int e = t; e < 2048; e += 256) {
        int n = e >> 7, k2 = e & 127;
        float x = (n < 8) ? ((k2 < 64) ? fsW2[k2 * 8 + n] : foW2[(k2 - 64) * 8 + n]) : 0.f;
        Wst2[n * HSTRIDE + k2] = f32_to_bf16(x);
    }

    const float* fsr = sf + (b * N_ + i) * FEAT_;
    const float* forr = of + (b * N_ + i) * FEAT_;
    float fsi[8], foi[8];
    #pragma unroll
    for (int u = 0; u < 8; u++) { fsi[u] = fsr[u]; foi[u] = forr[u]; }
    float b2s = fsb2[l15 & 7] + fob2[l15 & 7];

    __syncthreads();

    // hoist B-fragments to registers (proj-style LDS reads)
    bf16x8 Bf1[8], Bf2[4];
    #pragma unroll
    for (int nt = 0; nt < 8; nt++)
        Bf1[nt] = *(const bf16x8*)&Wst1[(nt * 16 + l15) * 40 + qd * 8];
    #pragma unroll
    for (int ks = 0; ks < 4; ks++)
        Bf2[ks] = *(const bf16x8*)&Wst2[l15 * HSTRIDE + ks * 32 + qd * 8];

    ushort* hb = hbuf[wave];
    #pragma unroll
    for (int qt = 0; qt < 4; qt++) {
        int j0 = (wave * 4 + qt) * 16;
        int j = j0 + l15;

        // ---- A-frag: qd0 |ds|, qd1 fs_j, qd2 |do|, qd3 fo_j ----
        const float* fr = ((qd < 2) ? sf : of) + (b * N_ + j) * FEAT_;
        float4 f0 = *(const float4*)&fr[0];
        float4 f1 = *(const float4*)&fr[4];
        float vals[8] = {f0.x, f0.y, f0.z, f0.w, f1.x, f1.y, f1.z, f1.w};
        if ((qd & 1) == 0) {
            const float* fi = (qd < 2) ? fsi : foi;
            #pragma unroll
            for (int u = 0; u < 8; u++) vals[u] = fabsf(vals[u] - fi[u]);
        }
        U8 au;
        #pragma unroll
        for (int u = 0; u < 8; u++) au.s[u] = f32_to_bf16(vals[u]);
        bf16x8 af = au.h;

        // ---- GEMM1: 8 n-tiles ----
        f32x4 S1[8];
        #pragma unroll
        for (int nt = 0; nt < 8; nt++) {
            f32x4 z = {};
            S1[nt] = __builtin_amdgcn_mfma_f32_16x16x32_bf16(af, Bf1[nt], z, 0, 0, 0);
        }

        // ---- epilogue: +his, relu, bf16 -> hbuf; plain ushort stores ----
        #pragma unroll
        for (int nt = 0; nt < 8; nt++) {
            float hv = hisbuf[nt * 16 + l15];
            #pragma unroll
            for (int r = 0; r < 4; r++) {
                float x = fmaxf(S1[nt][r] + hv, 0.f);
                hb[(qd * 4 + r) * HSTRIDE + nt * 16 + l15] = f32_to_bf16(x);
            }
        }
        __syncthreads();   // FENCE: h writes complete before GEMM2 reads

        // ---- GEMM2: K=128 in 4 steps; output cols 0..7 = heads ----
        f32x4 S2 = {};
        #pragma unroll
        for (int ks = 0; ks < 4; ks++) {
            bf16x8 a2 = *(const bf16x8*)&hb[l15 * HSTRIDE + ks * 32 + qd * 8];
            S2 = __builtin_amdgcn_mfma_f32_16x16x32_bf16(a2, Bf2[ks], S2, 0, 0, 0);
        }

        // ---- transpose 16j x 8h via tbuf ----
        if (l15 < 8) {
            #pragma unroll
            for (int r = 0; r < 4; r++)
                tbuf[wave][l15 * 16 + qd * 4 + r] = f32_to_bf16(LAM_ * (S2[r] + b2s));
        }
        __syncthreads();   // FENCE: tbuf writes complete before reads

        {
            int h2 = lane >> 3, jp = lane & 7;
            uint32_t lo = tbuf[wave][h2 * 16 + jp * 2];       // type-matched ushort reads
            uint32_t hi = tbuf[wave][h2 * 16 + jp * 2 + 1];
            uint32_t pk = lo | (hi << 16);
            *(uint32_t*)&mlpb[(((size_t)(b * H_ + h2) * N_ + i) * N_) + j0 + jp * 2] = pk;
        }
    }
}

// ---------- K4: MFMA attention (bias = tree fp32 + mlpb bf16) (unchanged) ----------
__global__ __launch_bounds__(256, 2) void attn_kernel(
    const ushort* __restrict__ qh, const ushort* __restrict__ kh,
    const ushort* __restrict__ vh, const float* __restrict__ tree,
    const ushort* __restrict__ mlpb, float* __restrict__ ctx)
{
    __shared__ __align__(16) ushort bufKP[256 * 72];
    __shared__ __align__(16) ushort bufV[64 * 264];

    int blk = blockIdx.x;
    int bh = blk >> 2;
    int quarter = blk & 3;

    int t = threadIdx.x;
    int wave = t >> 6, lane = t & 63;
    int l15 = lane & 15, qd = lane >> 4;
    int i0w = quarter * 64 + wave * 16;

    const ushort* khb = kh + (size_t)bh * N_ * DK_;
    const ushort* vhb = vh + (size_t)bh * N_ * DK_;

    #pragma unroll
    for (int u = t; u < 2048; u += 256) {
        int j = u >> 3, seg = (u & 7) * 8;
        uint4 kv = *(const uint4*)&khb[j * DK_ + seg];
        *(uint4*)&bufKP[j * 72 + seg] = kv;
    }
    #pragma unroll
    for (int u = t; u < 1024; u += 256) {
        int rp = u & 127, d0 = (u >> 7) * 8;
        U8 v0, v1;
        v0.u = *(const uint4*)&vhb[(2 * rp) * DK_ + d0];
        v1.u = *(const uint4*)&vhb[(2 * rp + 1) * DK_ + d0];
        #pragma unroll
        for (int jj = 0; jj < 8; jj++) {
            uint32_t pk = (uint32_t)v0.s[jj] | ((uint32_t)v1.s[jj] << 16);
            *(uint32_t*)&bufV[(d0 + jj) * 264 + 2 * rp] = pk;
        }
    }
    __syncthreads();

    bf16x8 a0, a1;
    {
        size_t qb = ((size_t)bh * N_ + i0w + l15) * DK_;
        U8 t0, t1;
        t0.u = *(const uint4*)&qh[qb + qd * 8];
        t1.u = *(const uint4*)&qh[qb + 32 + qd * 8];
        a0 = t0.h; a1 = t1.h;
    }
    f32x4 S[16];
    #pragma unroll
    for (int nt = 0; nt < 16; nt++) {
        f32x4 acc = {};
        bf16x8 b0 = *(const bf16x8*)&bufKP[(nt * 16 + l15) * 72 + qd * 8];
        bf16x8 b1 = *(const bf16x8*)&bufKP[(nt * 16 + l15) * 72 + 32 + qd * 8];
        acc = __builtin_amdgcn_mfma_f32_16x16x32_bf16(a0, b0, acc, 0, 0, 0);
        acc = __builtin_amdgcn_mfma_f32_16x16x32_bf16(a1, b1, acc, 0, 0, 0);
        S[nt] = acc;
    }

    {
        size_t base = ((size_t)bh * N_ + i0w + qd * 4) * N_ + l15;
        const float*  tr = tree + base;
        const ushort* mb = mlpb + base;
        #pragma unroll
        for (int nt = 0; nt < 16; nt++)
            #pragma unroll
            for (int r = 0; r < 4; r++)
                S[nt][r] += tr[(size_t)r * N_ + nt * 16] + bf16_to_f32(mb[(size_t)r * N_ + nt * 16]);
    }

    float mx[4], sm[4];
    #pragma unroll
    for (int r = 0; r < 4; r++) mx[r] = -1e30f;
    #pragma unroll
    for (int nt = 0; nt < 16; nt++)
        #pragma unroll
        for (int r = 0; r < 4; r++) mx[r] = fmaxf(mx[r], S[nt][r]);
    #pragma unroll
    for (int r = 0; r < 4; r++) {
        #pragma unroll
        for (int m = 1; m <= 8; m <<= 1) mx[r] = fmaxf(mx[r], __shfl_xor(mx[r], m));
    }
    #pragma unroll
    for (int r = 0; r < 4; r++) sm[r] = 0.f;
    #pragma unroll
    for (int nt = 0; nt < 16; nt++)
        #pragma unroll
        for (int r = 0; r < 4; r++) {
            float e = __expf(S[nt][r] - mx[r]);
            S[nt][r] = e;
            sm[r] += e;
        }
    #pragma unroll
    for (int r = 0; r < 4; r++) {
        #pragma unroll
        for (int m = 1; m <= 8; m <<= 1) sm[r] += __shfl_xor(sm[r], m);
        sm[r] = 1.0f / sm[r];
    }

    __syncthreads();

    {
        uint32_t* Pw = (uint32_t*)&bufKP[wave * 16 * 264];
        #pragma unroll
        for (int nt = 0; nt < 16; nt++)
            #pragma unroll
            for (int r = 0; r < 4; r++) {
                float p = S[nt][r] * sm[r];
                float po = __shfl_xor(p, 1);
                uint32_t pk = (uint32_t)f32_to_bf16(p) | ((uint32_t)f32_to_bf16(po) << 16);
                if ((lane & 1) == 0)
                    Pw[(qd * 4 + r) * 132 + nt * 8 + (l15 >> 1)] = pk;
            }
    }
    __syncthreads();   // FENCE: P writes complete before PV reads (same hazard class)

    const ushort* Pw = &bufKP[wave * 16 * 264];
    f32x4 O[4] = {};
    #pragma unroll
    for (int ks = 0; ks < 8; ks++) {
        int j0 = ks * 32;
        bf16x8 pa = *(const bf16x8*)&Pw[l15 * 264 + j0 + qd * 8];
        #pragma unroll
        for (int ntd = 0; ntd < 4; ntd++) {
            bf16x8 vb = *(const bf16x8*)&bufV[(ntd * 16 + l15) * 264 + j0 + qd * 8];
            O[ntd] = __builtin_amdgcn_mfma_f32_16x16x32_bf16(pa, vb, O[ntd], 0, 0, 0);
        }
    }

    #pragma unroll
    for (int ntd = 0; ntd < 4; ntd++)
        #pragma unroll
        for (int r = 0; r < 4; r++)
            ctx[((size_t)bh * N_ + i0w + qd * 4 + r) * DK_ + ntd * 16 + l15] = O[ntd][r];
}

// ---------- K5: output projection (fp32 tiled GEMM, unchanged) ----------
__global__ __launch_bounds__(256) void outproj_kernel(
    const float* __restrict__ ctx, const float* __restrict__ Wo,
    const float* __restrict__ bo, float* __restrict__ out)
{
    int rt0 = blockIdx.x * 64;
    int c0  = blockIdx.y * 64;
    __shared__ __align__(16) float Xs[16][68];
    __shared__ __align__(16) float Ws[16][68];
    int t = threadIdx.x;
    int tx = t & 15, ty = t >> 4;
    int lr = t >> 2, lk = (t & 3) * 4;
    int wk = t >> 4, wc = (t & 15) * 4;
    int r = rt0 + lr;
    int b_ = r >> 8, n_ = r & 255;
    float acc[4][4] = {};

    for (int k0 = 0; k0 < HID_; k0 += 16) {
        int kidx = k0 + lk;
        float4 xa = *(const float4*)&ctx[((b_ * H_ + (kidx >> 6)) * N_ + n_) * DK_ + (kidx & 63)];
        float4 wa = *(const float4*)&Wo[(k0 + wk) * HID_ + c0 + wc];
        __syncthreads();
        Xs[lk + 0][lr] = xa.x; Xs[lk + 1][lr] = xa.y;
        Xs[lk + 2][lr] = xa.z; Xs[lk + 3][lr] = xa.w;
        *(float4*)&Ws[wk][wc] = wa;
        __syncthreads();
        #pragma unroll
        for (int kk = 0; kk < 16; kk++) {
            float4 a4 = *(const float4*)&Xs[kk][ty * 4];
            float4 b4 = *(const float4*)&Ws[kk][tx * 4];
            float av[4] = {a4.x, a4.y, a4.z, a4.w};
            float bv4[4] = {b4.x, b4.y, b4.z, b4.w};
            #pragma unroll
            for (int i = 0; i < 4; i++)
                #pragma unroll
                for (int j = 0; j < 4; j++)
                    acc[i][j] += av[i] * bv4[j];
        }
    }

    float4 bv4 = *(const float4*)&bo[c0 + tx * 4];
    float bb[4] = {bv4.x, bv4.y, bv4.z, bv4.w};
    #pragma unroll
    for (int i = 0; i < 4; i++) {
        int rr = rt0 + ty * 4 + i;
        float4 o;
        o.x = acc[i][0] + bb[0]; o.y = acc[i][1] + bb[1];
        o.z = acc[i][2] + bb[2]; o.w = acc[i][3] + bb[3];
        *(float4*)&out[rr * HID_ + c0 + tx * 4] = o;
    }
}

// ---------- launch ----------
extern "C" void kernel_launch(void* const* d_in, const int* in_sizes, int n_in,
                              void* d_out, int out_size, void* d_ws, size_t ws_size,
                              hipStream_t stream)
{
    const float* q    = (const float*)d_in[0];
    const float* k    = (const float*)d_in[1];
    const float* v    = (const float*)d_in[2];
    const float* tree = (const float*)d_in[3];
    const float* sf   = (const float*)d_in[4];
    const float* of   = (const float*)d_in[5];
    const float* Wq   = (const float*)d_in[6];
    const float* bq   = (const float*)d_in[7];
    const float* Wk   = (const float*)d_in[8];
    const float* bk   = (const float*)d_in[9];
    const float* Wv   = (const float*)d_in[10];
    const float* bv   = (const float*)d_in[11];
    const float* Wo   = (const float*)d_in[12];
    const float* bo   = (const float*)d_in[13];
    const float* fsW1 = (const float*)d_in[14];
    const float* fsb1 = (const float*)d_in[15];
    const float* fsW2 = (const float*)d_in[16];
    const float* fsb2 = (const float*)d_in[17];
    const float* foW1 = (const float*)d_in[18];
    const float* fob1 = (const float*)d_in[19];
    const float* foW2 = (const float*)d_in[20];
    const float* fob2 = (const float*)d_in[21];

    char* ws = (char*)d_ws;
    ushort* qh     = (ushort*)(ws + 0);            // 4,194,304
    ushort* kh     = (ushort*)(ws + 4194304);      // 4,194,304
    ushort* vh     = (ushort*)(ws + 8388608);      // 4,194,304
    float*  ctx    = (float*)(ws + 12582912);      // 8,388,608
    float*  hisC   = (float*)(ws + 20971520);      // 2,097,152
    ushort* mlpb   = (ushort*)(ws + 23080960);     // 16,777,216

    proj_kernel<<<dim3(64, 8, 3), 256, 0, stream>>>(q, k, v, Wq, bq, Wk, bk, Wv, bv, qh, kh, vh);
    node_prep_kernel<<<2048, 256, 0, stream>>>(sf, of, fsW1, fsb1, foW1, fob1, hisC);
    pair_bias_mfma<<<dim3(N_, B_), 256, 0, stream>>>(sf, of, hisC, fsW1, foW1, fsW2, foW2,
                                                     fsb2, fob2, mlpb);
    attn_kernel<<<512, 256, 0, stream>>>(qh, kh, vh, tree, mlpb, ctx);
    outproj_kernel<<<dim3(64, 8), 256, 0, stream>>>(ctx, Wo, bo, (float*)d_out);
}

// Round 8
// 260.973 us; speedup vs baseline: 1.6971x; 1.0601x over previous
//
#include <hip/hip_runtime.h>
#include <hip/hip_bf16.h>
#include <stdint.h>

// Problem constants
#define B_    16
#define N_    256
#define HID_  512
#define H_    8
#define DK_   64
#define FEAT_ 8
#define MLPH_ 64
#define LAM_  0.1f
#define SCALE_ 0.125f   // DK^-0.5

typedef short bf16x8 __attribute__((ext_vector_type(8)));
typedef float f32x4  __attribute__((ext_vector_type(4)));

union U8 { uint4 u; bf16x8 h; ushort s[8]; };

__device__ __forceinline__ uint16_t f32_to_bf16(float x) {
    uint32_t u = __float_as_uint(x);
    u += 0x7fffu + ((u >> 16) & 1u);      // RNE (no NaN/Inf in this data)
    return (uint16_t)(u >> 16);
}
__device__ __forceinline__ float bf16_to_f32(uint16_t v) {
    return __uint_as_float(((uint32_t)v) << 16);
}
__device__ __forceinline__ uint32_t pk_bf16(float lo, float hi) {
    float2 xy; xy.x = lo; xy.y = hi;
    __hip_bfloat162 b2 = __float22bfloat162_rn(xy);   // HW packed cvt on gfx950
    return *(uint32_t*)&b2;                            // .x in low 16 bits
}

// ---------- K1: QKV projection, bf16 MFMA GEMM (unchanged) ----------
__global__ __launch_bounds__(256, 4) void proj_kernel(
    const float* __restrict__ q, const float* __restrict__ k, const float* __restrict__ v,
    const float* __restrict__ Wq, const float* __restrict__ bq,
    const float* __restrict__ Wk, const float* __restrict__ bk,
    const float* __restrict__ Wv, const float* __restrict__ bv,
    ushort* __restrict__ qh, ushort* __restrict__ kh, ushort* __restrict__ vh)
{
    int z = blockIdx.z;
    const float* X    = (z == 0) ? q  : (z == 1) ? k  : v;
    const float* W    = (z == 0) ? Wq : (z == 1) ? Wk : Wv;
    const float* bias = (z == 0) ? bq : (z == 1) ? bk : bv;
    ushort* out       = (z == 0) ? qh : (z == 1) ? kh : vh;
    float scale       = (z == 0) ? SCALE_ : 1.0f;

    int m0 = blockIdx.x * 64;
    int h  = blockIdx.y;
    int c0 = h * 64;

    __shared__ __align__(16) ushort Xs[64 * 40];
    __shared__ __align__(16) ushort Ws[64 * 40];

    int t = threadIdx.x;
    int wave = t >> 6, lane = t & 63;
    int l15 = lane & 15, qd = lane >> 4;

    f32x4 acc[4] = {};

    for (int k0 = 0; k0 < HID_; k0 += 32) {
        __syncthreads();
        #pragma unroll
        for (int u = t; u < 512; u += 256) {
            int r = u >> 3, c4 = (u & 7) * 4;
            float4 xv = *(const float4*)&X[(m0 + r) * HID_ + k0 + c4];
            ushort4 o;
            o.x = f32_to_bf16(xv.x); o.y = f32_to_bf16(xv.y);
            o.z = f32_to_bf16(xv.z); o.w = f32_to_bf16(xv.w);
            *(ushort4*)&Xs[r * 40 + c4] = o;
        }
        {
            int kr = t & 15, nq = t >> 4;
            float4 w0 = *(const float4*)&W[(k0 + 2 * kr) * HID_ + c0 + nq * 4];
            float4 w1 = *(const float4*)&W[(k0 + 2 * kr + 1) * HID_ + c0 + nq * 4];
            const float* a0 = &w0.x; const float* a1 = &w1.x;
            #pragma unroll
            for (int i = 0; i < 4; i++) {
                uint32_t pk = (uint32_t)f32_to_bf16(a0[i]) | ((uint32_t)f32_to_bf16(a1[i]) << 16);
                *(uint32_t*)&Ws[(nq * 4 + i) * 40 + 2 * kr] = pk;
            }
        }
        __syncthreads();
        bf16x8 af = *(const bf16x8*)&Xs[(wave * 16 + l15) * 40 + qd * 8];
        #pragma unroll
        for (int nt = 0; nt < 4; nt++) {
            bf16x8 bf = *(const bf16x8*)&Ws[(nt * 16 + l15) * 40 + qd * 8];
            acc[nt] = __builtin_amdgcn_mfma_f32_16x16x32_bf16(af, bf, acc[nt], 0, 0, 0);
        }
    }

    #pragma unroll
    for (int nt = 0; nt < 4; nt++) {
        float bb = bias[c0 + nt * 16 + l15];
        #pragma unroll
        for (int r = 0; r < 4; r++) {
            int m = m0 + wave * 16 + qd * 4 + r;
            int b_ = m >> 8, n_ = m & 255;
            float val = (acc[nt][r] + bb) * scale;
            out[(((b_ * H_ + h) * N_) + n_) * DK_ + nt * 16 + l15] = f32_to_bf16(val);
        }
    }
}

// ---------- K3: pair-MLP via MFMA -> mlpb = bf16(LAM*(mlp_s+mlp_o+b2)) ----------
// R8: his folded into MFMA C-operand; h columns pi-permuted (k2=(c&15)*8+(c>>4))
// so each lane's 8 GEMM1 outputs per row are contiguous -> relu + 4 packed cvt +
// ONE ds_write_b128 per row; LAM folded into staged W2; wave-local
// __threadfence_block() fences (hbuf/tbuf are per-wave) replace __syncthreads;
// his computed in-block (node_prep kernel deleted).
#define HSTRIDE 136
__global__ __launch_bounds__(256) void pair_bias_mfma(
    const float* __restrict__ sf, const float* __restrict__ of,
    const float* __restrict__ fsW1, const float* __restrict__ fsb1,
    const float* __restrict__ foW1, const float* __restrict__ fob1,
    const float* __restrict__ fsW2, const float* __restrict__ fsb2,
    const float* __restrict__ foW2, const float* __restrict__ fob2,
    ushort* __restrict__ mlpb)
{
    __shared__ __align__(16) ushort hbuf[4][16 * HSTRIDE];  // per-wave h
    __shared__ __align__(16) ushort Wst1[128 * 40];         // GEMM1 B: [n=128][k=32]
    __shared__ __align__(16) ushort Wst2[16 * HSTRIDE];     // GEMM2 B: [n=16][k2=128], pi-permuted, LAM-scaled
    __shared__ float hisbuf[128];
    __shared__ __align__(4) ushort tbuf[4][8 * 16];

    int i = blockIdx.x, b = blockIdx.y;
    int t = threadIdx.x;
    int wave = t >> 6, lane = t & 63;
    int l15 = lane & 15, qd = lane >> 4;

    // in-block his: hisbuf[c] = b1[c] + feat_i . W1a  (c<64: s-set, else o-set)
    if (t < 128) {
        int set = t >> 6, kk = t & 63;
        const float* W1 = set ? foW1 : fsW1;
        const float* fi = (set ? of : sf) + (b * N_ + i) * FEAT_;
        float a = (set ? fob1 : fsb1)[kk];
        #pragma unroll
        for (int f = 0; f < FEAT_; f++) a += fi[f] * W1[f * 64 + kk];
        hisbuf[t] = a;
    }

    // stage Wstack1 transposed [n][k]: k 0..7 = Wc_s, 8..15 = Wb_s (n<64);
    // 16..23 = Wc_o, 24..31 = Wb_o (n>=64); zero elsewhere.
    for (int e = t; e < 4096; e += 256) {
        int n = e >> 5, kk = e & 31, q = kk >> 3, u = kk & 7;
        float x = 0.f;
        if (n < 64) {
            if (q == 0) x = fsW1[(16 + u) * 64 + n];
            else if (q == 1) x = fsW1[(8 + u) * 64 + n];
        } else {
            int n2 = n - 64;
            if (q == 2) x = foW1[(16 + u) * 64 + n2];
            else if (q == 3) x = foW1[(8 + u) * 64 + n2];
        }
        Wst1[n * 40 + kk] = f32_to_bf16(x);
    }
    // stage Wstack2 [n][k2] under pi: c = ((k2&7)<<4)|(k2>>3); LAM pre-scaled.
    for (int e = t; e < 2048; e += 256) {
        int n = e >> 7, k2 = e & 127;
        int c = ((k2 & 7) << 4) | (k2 >> 3);
        float x = (n < 8) ? LAM_ * ((c < 64) ? fsW2[c * 8 + n] : foW2[(c - 64) * 8 + n]) : 0.f;
        Wst2[n * HSTRIDE + k2] = f32_to_bf16(x);
    }

    const float* fsr = sf + (b * N_ + i) * FEAT_;
    const float* forr = of + (b * N_ + i) * FEAT_;
    float fsi[8], foi[8];
    #pragma unroll
    for (int u = 0; u < 8; u++) { fsi[u] = fsr[u]; foi[u] = forr[u]; }
    float b2l = LAM_ * (fsb2[l15 & 7] + fob2[l15 & 7]);

    __syncthreads();   // cross-wave: Wst1/Wst2/hisbuf ready

    // hoist B-fragments and per-lane his to registers
    bf16x8 Bf1[8], Bf2[4];
    #pragma unroll
    for (int nt = 0; nt < 8; nt++)
        Bf1[nt] = *(const bf16x8*)&Wst1[(nt * 16 + l15) * 40 + qd * 8];
    #pragma unroll
    for (int ks = 0; ks < 4; ks++)
        Bf2[ks] = *(const bf16x8*)&Wst2[l15 * HSTRIDE + ks * 32 + qd * 8];
    float hv[8];
    #pragma unroll
    for (int nt = 0; nt < 8; nt++) hv[nt] = hisbuf[nt * 16 + l15];

    ushort* hb = hbuf[wave];
    #pragma unroll
    for (int qt = 0; qt < 4; qt++) {
        int j0 = (wave * 4 + qt) * 16;
        int j = j0 + l15;

        // ---- A-frag: qd0 |ds|, qd1 fs_j, qd2 |do|, qd3 fo_j ----
        const float* fr = ((qd < 2) ? sf : of) + (b * N_ + j) * FEAT_;
        float4 f0 = *(const float4*)&fr[0];
        float4 f1 = *(const float4*)&fr[4];
        float vals[8] = {f0.x, f0.y, f0.z, f0.w, f1.x, f1.y, f1.z, f1.w};
        if ((qd & 1) == 0) {
            const float* fi = (qd < 2) ? fsi : foi;
            #pragma unroll
            for (int u = 0; u < 8; u++) vals[u] = fabsf(vals[u] - fi[u]);
        }
        U8 au;
        #pragma unroll
        for (int p = 0; p < 4; p++)
            ((uint32_t*)&au)[p] = pk_bf16(vals[2 * p], vals[2 * p + 1]);
        bf16x8 af = au.h;

        // ---- GEMM1 with his in C-operand ----
        f32x4 S1[8];
        #pragma unroll
        for (int nt = 0; nt < 8; nt++) {
            f32x4 c0 = {hv[nt], hv[nt], hv[nt], hv[nt]};
            S1[nt] = __builtin_amdgcn_mfma_f32_16x16x32_bf16(af, Bf1[nt], c0, 0, 0, 0);
        }

        // ---- relu + packed cvt + one b128 write per row (pi layout) ----
        #pragma unroll
        for (int r = 0; r < 4; r++) {
            uint4 w;
            w.x = pk_bf16(fmaxf(S1[0][r], 0.f), fmaxf(S1[1][r], 0.f));
            w.y = pk_bf16(fmaxf(S1[2][r], 0.f), fmaxf(S1[3][r], 0.f));
            w.z = pk_bf16(fmaxf(S1[4][r], 0.f), fmaxf(S1[5][r], 0.f));
            w.w = pk_bf16(fmaxf(S1[6][r], 0.f), fmaxf(S1[7][r], 0.f));
            *(uint4*)&hb[(qd * 4 + r) * HSTRIDE + l15 * 8] = w;
        }
        __threadfence_block();   // wave-local fence: h writes before GEMM2 reads

        // ---- GEMM2: K=128 (pi-consistent), C-init = LAM*b2 ----
        f32x4 S2 = {b2l, b2l, b2l, b2l};
        #pragma unroll
        for (int ks = 0; ks < 4; ks++) {
            bf16x8 a2 = *(const bf16x8*)&hb[l15 * HSTRIDE + ks * 32 + qd * 8];
            S2 = __builtin_amdgcn_mfma_f32_16x16x32_bf16(a2, Bf2[ks], S2, 0, 0, 0);
        }

        // ---- transpose 16j x 8h via tbuf (per-wave), write coalesced ----
        if (l15 < 8) {
            #pragma unroll
            for (int r = 0; r < 4; r++)
                tbuf[wave][l15 * 16 + qd * 4 + r] = f32_to_bf16(S2[r]);
        }
        __threadfence_block();   // wave-local fence: tbuf writes before reads

        {
            int h2 = lane >> 3, jp = lane & 7;
            uint32_t lo = tbuf[wave][h2 * 16 + jp * 2];
            uint32_t hi = tbuf[wave][h2 * 16 + jp * 2 + 1];
            uint32_t pk = lo | (hi << 16);
            *(uint32_t*)&mlpb[(((size_t)(b * H_ + h2) * N_ + i) * N_) + j0 + jp * 2] = pk;
        }
    }
}

// ---------- K4: MFMA attention (ctx now bf16) ----------
__global__ __launch_bounds__(256, 2) void attn_kernel(
    const ushort* __restrict__ qh, const ushort* __restrict__ kh,
    const ushort* __restrict__ vh, const float* __restrict__ tree,
    const ushort* __restrict__ mlpb, ushort* __restrict__ ctxb)
{
    __shared__ __align__(16) ushort bufKP[256 * 72];
    __shared__ __align__(16) ushort bufV[64 * 264];

    int blk = blockIdx.x;
    int bh = blk >> 2;
    int quarter = blk & 3;

    int t = threadIdx.x;
    int wave = t >> 6, lane = t & 63;
    int l15 = lane & 15, qd = lane >> 4;
    int i0w = quarter * 64 + wave * 16;

    const ushort* khb = kh + (size_t)bh * N_ * DK_;
    const ushort* vhb = vh + (size_t)bh * N_ * DK_;

    #pragma unroll
    for (int u = t; u < 2048; u += 256) {
        int j = u >> 3, seg = (u & 7) * 8;
        uint4 kv = *(const uint4*)&khb[j * DK_ + seg];
        *(uint4*)&bufKP[j * 72 + seg] = kv;
    }
    #pragma unroll
    for (int u = t; u < 1024; u += 256) {
        int rp = u & 127, d0 = (u >> 7) * 8;
        U8 v0, v1;
        v0.u = *(const uint4*)&vhb[(2 * rp) * DK_ + d0];
        v1.u = *(const uint4*)&vhb[(2 * rp + 1) * DK_ + d0];
        #pragma unroll
        for (int jj = 0; jj < 8; jj++) {
            uint32_t pk = (uint32_t)v0.s[jj] | ((uint32_t)v1.s[jj] << 16);
            *(uint32_t*)&bufV[(d0 + jj) * 264 + 2 * rp] = pk;
        }
    }
    __syncthreads();

    bf16x8 a0, a1;
    {
        size_t qb = ((size_t)bh * N_ + i0w + l15) * DK_;
        U8 t0, t1;
        t0.u = *(const uint4*)&qh[qb + qd * 8];
        t1.u = *(const uint4*)&qh[qb + 32 + qd * 8];
        a0 = t0.h; a1 = t1.h;
    }
    f32x4 S[16];
    #pragma unroll
    for (int nt = 0; nt < 16; nt++) {
        f32x4 acc = {};
        bf16x8 b0 = *(const bf16x8*)&bufKP[(nt * 16 + l15) * 72 + qd * 8];
        bf16x8 b1 = *(const bf16x8*)&bufKP[(nt * 16 + l15) * 72 + 32 + qd * 8];
        acc = __builtin_amdgcn_mfma_f32_16x16x32_bf16(a0, b0, acc, 0, 0, 0);
        acc = __builtin_amdgcn_mfma_f32_16x16x32_bf16(a1, b1, acc, 0, 0, 0);
        S[nt] = acc;
    }

    {
        size_t base = ((size_t)bh * N_ + i0w + qd * 4) * N_ + l15;
        const float*  tr = tree + base;
        const ushort* mb = mlpb + base;
        #pragma unroll
        for (int nt = 0; nt < 16; nt++)
            #pragma unroll
            for (int r = 0; r < 4; r++)
                S[nt][r] += tr[(size_t)r * N_ + nt * 16] + bf16_to_f32(mb[(size_t)r * N_ + nt * 16]);
    }

    float mx[4], sm[4];
    #pragma unroll
    for (int r = 0; r < 4; r++) mx[r] = -1e30f;
    #pragma unroll
    for (int nt = 0; nt < 16; nt++)
        #pragma unroll
        for (int r = 0; r < 4; r++) mx[r] = fmaxf(mx[r], S[nt][r]);
    #pragma unroll
    for (int r = 0; r < 4; r++) {
        #pragma unroll
        for (int m = 1; m <= 8; m <<= 1) mx[r] = fmaxf(mx[r], __shfl_xor(mx[r], m));
    }
    #pragma unroll
    for (int r = 0; r < 4; r++) sm[r] = 0.f;
    #pragma unroll
    for (int nt = 0; nt < 16; nt++)
        #pragma unroll
        for (int r = 0; r < 4; r++) {
            float e = __expf(S[nt][r] - mx[r]);
            S[nt][r] = e;
            sm[r] += e;
        }
    #pragma unroll
    for (int r = 0; r < 4; r++) {
        #pragma unroll
        for (int m = 1; m <= 8; m <<= 1) sm[r] += __shfl_xor(sm[r], m);
        sm[r] = 1.0f / sm[r];
    }

    __syncthreads();

    {
        uint32_t* Pw = (uint32_t*)&bufKP[wave * 16 * 264];
        #pragma unroll
        for (int nt = 0; nt < 16; nt++)
            #pragma unroll
            for (int r = 0; r < 4; r++) {
                float p = S[nt][r] * sm[r];
                float po = __shfl_xor(p, 1);
                uint32_t pk = (uint32_t)f32_to_bf16(p) | ((uint32_t)f32_to_bf16(po) << 16);
                if ((lane & 1) == 0)
                    Pw[(qd * 4 + r) * 132 + nt * 8 + (l15 >> 1)] = pk;
            }
    }
    __syncthreads();   // FENCE: P writes complete before PV reads

    const ushort* Pw = &bufKP[wave * 16 * 264];
    f32x4 O[4] = {};
    #pragma unroll
    for (int ks = 0; ks < 8; ks++) {
        int j0 = ks * 32;
        bf16x8 pa = *(const bf16x8*)&Pw[l15 * 264 + j0 + qd * 8];
        #pragma unroll
        for (int ntd = 0; ntd < 4; ntd++) {
            bf16x8 vb = *(const bf16x8*)&bufV[(ntd * 16 + l15) * 264 + j0 + qd * 8];
            O[ntd] = __builtin_amdgcn_mfma_f32_16x16x32_bf16(pa, vb, O[ntd], 0, 0, 0);
        }
    }

    #pragma unroll
    for (int ntd = 0; ntd < 4; ntd++)
        #pragma unroll
        for (int r = 0; r < 4; r++)
            ctxb[((size_t)bh * N_ + i0w + qd * 4 + r) * DK_ + ntd * 16 + l15] =
                f32_to_bf16(O[ntd][r]);
}

// ---------- K5: output projection, bf16 MFMA (proj_kernel clone; A = bf16 ctx) --
__global__ __launch_bounds__(256, 4) void outproj_kernel(
    const ushort* __restrict__ ctxb, const float* __restrict__ Wo,
    const float* __restrict__ bo, float* __restrict__ out)
{
    int m0 = blockIdx.x * 64;
    int c0 = blockIdx.y * 64;

    __shared__ __align__(16) ushort Xs[64 * 40];
    __shared__ __align__(16) ushort Ws[64 * 40];

    int t = threadIdx.x;
    int wave = t >> 6, lane = t & 63;
    int l15 = lane & 15, qd = lane >> 4;

    f32x4 acc[4] = {};

    for (int k0 = 0; k0 < HID_; k0 += 32) {
        __syncthreads();
        // stage A: ctx bf16, head = k0>>6 (chunk never crosses a head boundary)
        {
            int r = t >> 2, s8 = (t & 3) * 8;
            int m = m0 + r, b_ = m >> 8, n_ = m & 255;
            uint4 xv = *(const uint4*)&ctxb[(((b_ * H_ + (k0 >> 6)) * N_) + n_) * DK_ + (k0 & 63) + s8];
            *(uint4*)&Xs[r * 40 + s8] = xv;
        }
        // stage W tile 32x64 transposed, packed k-pairs (proj pattern)
        {
            int kr = t & 15, nq = t >> 4;
            float4 w0 = *(const float4*)&Wo[(k0 + 2 * kr) * HID_ + c0 + nq * 4];
            float4 w1 = *(const float4*)&Wo[(k0 + 2 * kr + 1) * HID_ + c0 + nq * 4];
            const float* a0 = &w0.x; const float* a1 = &w1.x;
            #pragma unroll
            for (int i = 0; i < 4; i++) {
                uint32_t pk = (uint32_t)f32_to_bf16(a0[i]) | ((uint32_t)f32_to_bf16(a1[i]) << 16);
                *(uint32_t*)&Ws[(nq * 4 + i) * 40 + 2 * kr] = pk;
            }
        }
        __syncthreads();
        bf16x8 af = *(const bf16x8*)&Xs[(wave * 16 + l15) * 40 + qd * 8];
        #pragma unroll
        for (int nt = 0; nt < 4; nt++) {
            bf16x8 bf = *(const bf16x8*)&Ws[(nt * 16 + l15) * 40 + qd * 8];
            acc[nt] = __builtin_amdgcn_mfma_f32_16x16x32_bf16(af, bf, acc[nt], 0, 0, 0);
        }
    }

    #pragma unroll
    for (int nt = 0; nt < 4; nt++) {
        float bb = bo[c0 + nt * 16 + l15];
        #pragma unroll
        for (int r = 0; r < 4; r++) {
            int m = m0 + wave * 16 + qd * 4 + r;
            out[m * HID_ + c0 + nt * 16 + l15] = acc[nt][r] + bb;
        }
    }
}

// ---------- launch ----------
extern "C" void kernel_launch(void* const* d_in, const int* in_sizes, int n_in,
                              void* d_out, int out_size, void* d_ws, size_t ws_size,
                              hipStream_t stream)
{
    const float* q    = (const float*)d_in[0];
    const float* k    = (const float*)d_in[1];
    const float* v    = (const float*)d_in[2];
    const float* tree = (const float*)d_in[3];
    const float* sf   = (const float*)d_in[4];
    const float* of   = (const float*)d_in[5];
    const float* Wq   = (const float*)d_in[6];
    const float* bq   = (const float*)d_in[7];
    const float* Wk   = (const float*)d_in[8];
    const float* bk   = (const float*)d_in[9];
    const float* Wv   = (const float*)d_in[10];
    const float* bv   = (const float*)d_in[11];
    const float* Wo   = (const float*)d_in[12];
    const float* bo   = (const float*)d_in[13];
    const float* fsW1 = (const float*)d_in[14];
    const float* fsb1 = (const float*)d_in[15];
    const float* fsW2 = (const float*)d_in[16];
    const float* fsb2 = (const float*)d_in[17];
    const float* foW1 = (const float*)d_in[18];
    const float* fob1 = (const float*)d_in[19];
    const float* foW2 = (const float*)d_in[20];
    const float* fob2 = (const float*)d_in[21];

    char* ws = (char*)d_ws;
    ushort* qh     = (ushort*)(ws + 0);            // 4,194,304
    ushort* kh     = (ushort*)(ws + 4194304);      // 4,194,304
    ushort* vh     = (ushort*)(ws + 8388608);      // 4,194,304
    ushort* ctxb   = (ushort*)(ws + 12582912);     // 4,194,304 (bf16 now)
    ushort* mlpb   = (ushort*)(ws + 23080960);     // 16,777,216

    proj_kernel<<<dim3(64, 8, 3), 256, 0, stream>>>(q, k, v, Wq, bq, Wk, bk, Wv, bv, qh, kh, vh);
    pair_bias_mfma<<<dim3(N_, B_), 256, 0, stream>>>(sf, of, fsW1, fsb1, foW1, fob1,
                                                     fsW2, fsb2, foW2, fob2, mlpb);
    attn_kernel<<<512, 256, 0, stream>>>(qh, kh, vh, tree, mlpb, ctxb);
    outproj_kernel<<<dim3(64, 8), 256, 0, stream>>>(ctxb, Wo, bo, (float*)d_out);
}